// Round 3
// baseline (301.041 us; speedup 1.0000x reference)
//
#include <hip/hip_runtime.h>
#include <hip/hip_bf16.h>
#include <math.h>

// Problem constants
#define B_   128
#define C_   256
#define K_   64     // HZ*WZ (corr rows / channels)
#define N_   1024   // HX*WX (corr cols)
#define H_   32
#define W_   32
#define TC_  8
#define L_   64     // 2*H
#define EPS_ 1e-5f

// ---------------------------------------------------------------------------
// Kernel A: per-batch corr = z^T x (64 x 1024, K=256). Pure GEMM, corr -> d_out.
// grid (4 n-tiles, 128 batches) = 512 blocks (2/CU), block 256.
// Block tile 64k x 256n; per-thread 8x8 (LDS/VALU ratio 0.25).
// Single 40KB LDS buffer, c-step 32, T14 reg-staged pipeline:
//   barrier; ds_write(regs); barrier; issue next global loads -> regs; compute.
// x slots (16B) stored at phys sigma(s)=s^((s>>4)&1): balances bank groups on
// both the linear write (8 lanes/group) and the strided pair-read (4 lanes/group).
// ---------------------------------------------------------------------------
__global__ __launch_bounds__(256, 2) void kA_corr(const float* __restrict__ z,
                                                  const float* __restrict__ x,
                                                  float* __restrict__ corr)
{
    __shared__ float zs[32][64];    // 8 KB   [c][k]
    __shared__ float xs[32][256];   // 32 KB  [c][n] (16B slots swizzled)

    const int nt  = blockIdx.x;     // 0..3
    const int b   = blockIdx.y;
    const int tid = threadIdx.x;
    const int tk  = tid >> 5;       // 0..7 -> k0 = tk*8
    const int tn  = tid & 31;       // 0..31 -> n0 = tn*8

    const float* zb = z + (size_t)b * C_ * K_;
    const float* xb = x + (size_t)b * C_ * N_ + nt * 256;

    // staging coords (per thread)
    const int zrow = tid >> 4;          // + i*16, i=0..1
    const int zcol = (tid & 15) << 2;
    const int xrow = tid >> 6;          // + i*4,  i=0..7
    const int sq   = tid & 63;
    const int sph  = sq ^ ((sq >> 4) & 1);

    // read-side phys slots for this thread's 8 x floats (2 16B slots)
    const int s0 = (2 * tn) ^ (((2 * tn) >> 4) & 1);
    const int s1 = (2 * tn + 1) ^ (((2 * tn + 1) >> 4) & 1);

    const float* zg = zb + (size_t)zrow * K_ + zcol;
    const float* xg = xb + (size_t)xrow * N_ + sq * 4;

    float4 zr[2], xr[8];
    float  acc[8][8] = {};

    // prologue: load c-step 0 into regs
    #pragma unroll
    for (int i = 0; i < 2; ++i) zr[i] = *(const float4*)(zg + (size_t)i * 16 * K_);
    #pragma unroll
    for (int i = 0; i < 8; ++i) xr[i] = *(const float4*)(xg + (size_t)i * 4 * N_);

    for (int cs = 0; cs < 8; ++cs) {
        __syncthreads();   // readers of previous step done
        #pragma unroll
        for (int i = 0; i < 2; ++i) *(float4*)&zs[zrow + i * 16][zcol] = zr[i];
        #pragma unroll
        for (int i = 0; i < 8; ++i) *(float4*)&xs[xrow + i * 4][sph * 4] = xr[i];
        __syncthreads();

        if (cs < 7) {      // issue next step's loads; in flight during compute
            const float* zgn = zg + (size_t)(cs + 1) * 32 * K_;
            const float* xgn = xg + (size_t)(cs + 1) * 32 * N_;
            #pragma unroll
            for (int i = 0; i < 2; ++i) zr[i] = *(const float4*)(zgn + (size_t)i * 16 * K_);
            #pragma unroll
            for (int i = 0; i < 8; ++i) xr[i] = *(const float4*)(xgn + (size_t)i * 4 * N_);
        }

        #pragma unroll 8
        for (int c = 0; c < 32; ++c) {
            float4 z0 = *(float4*)&zs[c][tk * 8];
            float4 z1 = *(float4*)&zs[c][tk * 8 + 4];
            float4 x0 = *(float4*)&xs[c][s0 * 4];
            float4 x1 = *(float4*)&xs[c][s1 * 4];
            float za[8] = {z0.x, z0.y, z0.z, z0.w, z1.x, z1.y, z1.z, z1.w};
            float xa[8];
            // undo possible slot swap: s0 holds logical slot (2tn)^b4 data...
            // note: sigma only swaps the PAIR order when bit4 is set; we read
            // phys sigma(2tn) and sigma(2tn+1) which are exactly logical
            // 2tn and 2tn+1 in order. So xa is simply [x0, x1].
            xa[0] = x0.x; xa[1] = x0.y; xa[2] = x0.z; xa[3] = x0.w;
            xa[4] = x1.x; xa[5] = x1.y; xa[6] = x1.z; xa[7] = x1.w;
            #pragma unroll
            for (int i = 0; i < 8; ++i)
                #pragma unroll
                for (int j = 0; j < 8; ++j)
                    acc[i][j] = fmaf(za[i], xa[j], acc[i][j]);
        }
    }

    // corr tile write (into d_out)
    float* cb = corr + (size_t)b * K_ * N_ + nt * 256;
    #pragma unroll
    for (int i = 0; i < 8; ++i) {
        float4 lo = make_float4(acc[i][0], acc[i][1], acc[i][2], acc[i][3]);
        float4 hi = make_float4(acc[i][4], acc[i][5], acc[i][6], acc[i][7]);
        *(float4*)&cb[(size_t)(tk * 8 + i) * N_ + tn * 8]     = lo;
        *(float4*)&cb[(size_t)(tk * 8 + i) * N_ + tn * 8 + 4] = hi;
    }
}

// ---------------------------------------------------------------------------
// Kernel B: pooling (x_h, x_w from corr) + conv1 + per-batch BN partial sums.
// grid 128 (one block per batch), block 256. Reads corr (L2/L3-resident).
// ---------------------------------------------------------------------------
__global__ __launch_bounds__(256) void kB_pool(const float* __restrict__ corr,
                                               const float* __restrict__ w1,
                                               const float* __restrict__ b1,
                                               float* __restrict__ ypre,
                                               float* __restrict__ psum)
{
    __shared__ float rs[4][1024];   // 16 KB: 4 channels of corr
    __shared__ float xc[64][64];    // 16 KB: xcat  [channel][l]
    __shared__ float w1s[TC_ * 64];
    __shared__ float ys[TC_ * 64];

    const int b   = blockIdx.x;
    const int tid = threadIdx.x;
    const float* cb = corr + (size_t)b * K_ * N_;

    if (tid < 128) *(float4*)&w1s[tid * 4] = *(const float4*)&w1[tid * 4];

    for (int pass = 0; pass < 16; ++pass) {
        #pragma unroll
        for (int i = 0; i < 4; ++i) {
            int q   = tid + i * 256;          // f4 id within 4-channel slab
            int kcl = q >> 8;
            int off = (q & 255) * 4;
            *(float4*)&rs[kcl][off] =
                *(const float4*)&cb[(size_t)(pass * 4 + kcl) * N_ + off];
        }
        __syncthreads();

        if (tid < 128) {                      // x_h: (kcl, h) sums over w
            int kcl = tid >> 5, h = tid & 31;
            float s = 0.f;
            #pragma unroll
            for (int m = 0; m < 8; ++m) {     // rotate f4 start by h: bank-balanced
                float4 v = *(float4*)&rs[kcl][h * 32 + (((m + h) & 7) << 2)];
                s += v.x + v.y + v.z + v.w;
            }
            xc[pass * 4 + kcl][h] = s * (1.f / 32.f);
        } else {                              // x_w: (kcl, w) sums over h
            int kcl = (tid - 128) >> 5, w = (tid - 128) & 31;
            float s = 0.f;
            #pragma unroll
            for (int h2 = 0; h2 < 32; ++h2) s += rs[kcl][h2 * 32 + w];
            xc[pass * 4 + kcl][32 + w] = s * (1.f / 32.f);
        }
        __syncthreads();
    }

    // conv1: y[o][l] = sum_k w1[o][k] * xc[k][l] + b1[o]
    const int o0 = tid >> 6;       // wave-uniform
    const int l  = tid & 63;
    float y0 = 0.f, y1 = 0.f;
    #pragma unroll 8
    for (int k = 0; k < 64; ++k) {
        float xv = xc[k][l];
        y0 = fmaf(w1s[o0 * 64 + k],       xv, y0);
        y1 = fmaf(w1s[(o0 + 4) * 64 + k], xv, y1);
    }
    y0 += b1[o0];
    y1 += b1[o0 + 4];
    ypre[((size_t)b * TC_ + o0)     * L_ + l] = y0;
    ypre[((size_t)b * TC_ + o0 + 4) * L_ + l] = y1;
    ys[o0 * L_ + l]       = y0;
    ys[(o0 + 4) * L_ + l] = y1;
    __syncthreads();

    if (tid < TC_) {               // per-batch BN partials (no atomics)
        float s = 0.f, sq = 0.f;
        #pragma unroll
        for (int m = 0; m < 16; ++m) {
            float4 v = *(float4*)&ys[tid * 64 + m * 4];
            s  += v.x + v.y + v.z + v.w;
            sq += v.x * v.x + v.y * v.y + v.z * v.z + v.w * v.w;
        }
        psum[b * 16 + tid]       = s;
        psum[b * 16 + 8 + tid]   = sq;
    }
}

// ---------------------------------------------------------------------------
// Kernel D: reduce BN partials, BN apply + h-swish, conv2/conv3 + sigmoid.
// grid 128, block 256.
// ---------------------------------------------------------------------------
__global__ __launch_bounds__(256) void kD_gate(const float* __restrict__ ypre,
                                               const float* __restrict__ psum,
                                               const float* __restrict__ gamma,
                                               const float* __restrict__ beta,
                                               const float* __restrict__ w2,
                                               const float* __restrict__ b2,
                                               const float* __restrict__ w3,
                                               const float* __restrict__ b3,
                                               float* __restrict__ outh,
                                               float* __restrict__ outw)
{
    __shared__ float sred[16][17];
    __shared__ float stats[16];
    __shared__ float yn[TC_ * L_];
    __shared__ float w2s[K_ * TC_];
    __shared__ float w3s[K_ * TC_];
    __shared__ float b2s[K_], b3s[K_];

    const int b   = blockIdx.x;
    const int tid = threadIdx.x;

    {   // reduce psum[128][16] -> stats[16]
        float p = 0.f;
        #pragma unroll
        for (int m = 0; m < 8; ++m) p += psum[tid + 256 * m];
        sred[tid & 15][tid >> 4] = p;
    }
    __syncthreads();
    if (tid < 16) {
        float s = 0.f;
        #pragma unroll
        for (int c = 0; c < 16; ++c) s += sred[tid][c];
        stats[tid] = s;
    }
    __syncthreads();

    const float inv_n = 1.f / (float)(B_ * L_);
    #pragma unroll
    for (int r = 0; r < 2; ++r) {
        int idx = tid + r * 256;
        int o   = idx >> 6;
        float mu  = stats[o] * inv_n;
        float var = stats[8 + o] * inv_n - mu * mu;
        float v = ypre[(size_t)b * TC_ * L_ + idx];
        v = (v - mu) * (1.f / sqrtf(var + EPS_)) * gamma[o] + beta[o];
        v = v * fminf(fmaxf(v + 3.f, 0.f), 6.f) * (1.f / 6.f);   // h_swish
        yn[idx] = v;
    }
    if (tid < 128)      *(float4*)&w2s[tid * 4]         = *(const float4*)&w2[tid * 4];
    else                *(float4*)&w3s[(tid - 128) * 4] = *(const float4*)&w3[(tid - 128) * 4];
    if (tid < 64)       b2s[tid]      = b2[tid];
    else if (tid < 128) b3s[tid - 64] = b3[tid - 64];
    __syncthreads();

    #pragma unroll
    for (int r = 0; r < 16; ++r) {
        int idx   = tid + r * 256;
        int which = idx >> 11;              // 0: out_h, 1: out_w
        int o     = (idx >> 5) & 63;
        int p     = idx & 31;
        const float* wsm = which ? w3s : w2s;
        const float* bsm = which ? b3s : b2s;
        float s = bsm[o];
        #pragma unroll
        for (int tt = 0; tt < TC_; ++tt)
            s = fmaf(wsm[o * TC_ + tt], yn[tt * L_ + which * H_ + p], s);
        s = 1.f / (1.f + __expf(-s));
        float* dst = which ? outw : outh;
        dst[((size_t)b * K_ + o) * H_ + p] = s;
    }
}

// ---------------------------------------------------------------------------
// Kernel E: out = corr * out_w[w] * out_h[h], in place on d_out. float4.
// ---------------------------------------------------------------------------
__global__ __launch_bounds__(256) void kE_final(float* __restrict__ out,
                                                const float* __restrict__ outh,
                                                const float* __restrict__ outw)
{
    int idx = blockIdx.x * 256 + threadIdx.x;   // f4 index
    int w4 = idx & 7;
    int h  = (idx >> 3) & 31;
    int bk = idx >> 8;                          // b*64 + k
    float4 c4 = ((const float4*)out)[idx];
    float  oh = outh[bk * H_ + h];
    float4 ow = *(const float4*)&outw[bk * H_ + w4 * 4];
    c4.x *= ow.x * oh;
    c4.y *= ow.y * oh;
    c4.z *= ow.z * oh;
    c4.w *= ow.w * oh;
    ((float4*)out)[idx] = c4;
}

// ---------------------------------------------------------------------------
extern "C" void kernel_launch(void* const* d_in, const int* in_sizes, int n_in,
                              void* d_out, int out_size, void* d_ws, size_t ws_size,
                              hipStream_t stream)
{
    const float* z     = (const float*)d_in[0];
    const float* x     = (const float*)d_in[1];
    const float* w1    = (const float*)d_in[2];
    const float* b1    = (const float*)d_in[3];
    const float* gamma = (const float*)d_in[4];
    const float* beta  = (const float*)d_in[5];
    const float* w2    = (const float*)d_in[6];
    const float* b2    = (const float*)d_in[7];
    const float* w3    = (const float*)d_in[8];
    const float* b3    = (const float*)d_in[9];
    float* out = (float*)d_out;
    float* ws  = (float*)d_ws;

    // workspace layout (floats), total 591,872 (~2.37 MB)
    float* ypre = ws;                  // B*8*64  = 65536
    float* psum = ws + 65536;          // B*16    = 2048
    float* outh = ws + 67584;          // B*64*32 = 262144
    float* outw = ws + 329728;         // B*64*32 = 262144

    kA_corr <<<dim3(4, B_), 256, 0, stream>>>(z, x, out);
    kB_pool <<<B_,          256, 0, stream>>>(out, w1, b1, ypre, psum);
    kD_gate <<<B_,          256, 0, stream>>>(ypre, psum, gamma, beta,
                                              w2, b2, w3, b3, outh, outw);
    kE_final<<<(B_ * K_ * N_) / (256 * 4), 256, 0, stream>>>(out, outh, outw);
}

// Round 4
// 299.391 us; speedup vs baseline: 1.0055x; 1.0055x over previous
//
#include <hip/hip_runtime.h>
#include <hip/hip_bf16.h>
#include <math.h>

// Problem constants
#define B_   128
#define C_   256
#define K_   64     // HZ*WZ (corr rows / channels)
#define N_   1024   // HX*WX (corr cols)
#define H_   32
#define W_   32
#define TC_  8
#define L_   64     // 2*H
#define EPS_ 1e-5f

// ---------------------------------------------------------------------------
// Kernel A: per-batch corr = z^T x (64 x 1024, K=256). Pure GEMM, corr -> d_out.
// grid (4 n-tiles, 128 batches) = 512 blocks (2/CU), block 256.
// Block tile 64k x 256n; per-thread 8x8 (LDS/VALU ratio 0.25).
// Single 40KB LDS buffer, c-step 32, T14 reg-staged pipeline:
//   barrier; ds_write(regs); barrier; issue next global loads -> regs; compute.
// x slots (16B) stored at phys sigma(s)=s^((s>>4)&1): balances bank groups on
// both the linear write (8 lanes/group) and the strided pair-read (4 lanes/group).
// NOTE: __launch_bounds__(256, 1) — round 3's (256,2) capped VGPRs at 64 and
// spilled acc+staging to scratch (+152 MB HBM write traffic). Round 2 proved
// (256,1) gives VGPR~132, no spill.
// ---------------------------------------------------------------------------
__global__ __launch_bounds__(256, 1) void kA_corr(const float* __restrict__ z,
                                                  const float* __restrict__ x,
                                                  float* __restrict__ corr)
{
    __shared__ float zs[32][64];    // 8 KB   [c][k]
    __shared__ float xs[32][256];   // 32 KB  [c][n] (16B slots swizzled)

    const int nt  = blockIdx.x;     // 0..3
    const int b   = blockIdx.y;
    const int tid = threadIdx.x;
    const int tk  = tid >> 5;       // 0..7 -> k0 = tk*8
    const int tn  = tid & 31;       // 0..31 -> n0 = tn*8

    const float* zb = z + (size_t)b * C_ * K_;
    const float* xb = x + (size_t)b * C_ * N_ + nt * 256;

    // staging coords (per thread)
    const int zrow = tid >> 4;          // + i*16, i=0..1
    const int zcol = (tid & 15) << 2;
    const int xrow = tid >> 6;          // + i*4,  i=0..7
    const int sq   = tid & 63;
    const int sph  = sq ^ ((sq >> 4) & 1);

    // read-side phys slots for this thread's 8 x floats (2 16B slots)
    const int s0 = (2 * tn) ^ (((2 * tn) >> 4) & 1);
    const int s1 = (2 * tn + 1) ^ (((2 * tn + 1) >> 4) & 1);

    const float* zg = zb + (size_t)zrow * K_ + zcol;
    const float* xg = xb + (size_t)xrow * N_ + sq * 4;

    float4 zr[2], xr[8];
    float  acc[8][8] = {};

    // prologue: load c-step 0 into regs
    #pragma unroll
    for (int i = 0; i < 2; ++i) zr[i] = *(const float4*)(zg + (size_t)i * 16 * K_);
    #pragma unroll
    for (int i = 0; i < 8; ++i) xr[i] = *(const float4*)(xg + (size_t)i * 4 * N_);

    for (int cs = 0; cs < 8; ++cs) {
        __syncthreads();   // readers of previous step done
        #pragma unroll
        for (int i = 0; i < 2; ++i) *(float4*)&zs[zrow + i * 16][zcol] = zr[i];
        #pragma unroll
        for (int i = 0; i < 8; ++i) *(float4*)&xs[xrow + i * 4][sph * 4] = xr[i];
        __syncthreads();

        if (cs < 7) {      // issue next step's loads; in flight during compute
            const float* zgn = zg + (size_t)(cs + 1) * 32 * K_;
            const float* xgn = xg + (size_t)(cs + 1) * 32 * N_;
            #pragma unroll
            for (int i = 0; i < 2; ++i) zr[i] = *(const float4*)(zgn + (size_t)i * 16 * K_);
            #pragma unroll
            for (int i = 0; i < 8; ++i) xr[i] = *(const float4*)(xgn + (size_t)i * 4 * N_);
        }

        #pragma unroll 4
        for (int c = 0; c < 32; ++c) {
            float4 z0 = *(float4*)&zs[c][tk * 8];
            float4 z1 = *(float4*)&zs[c][tk * 8 + 4];
            float4 x0 = *(float4*)&xs[c][s0 * 4];
            float4 x1 = *(float4*)&xs[c][s1 * 4];
            float za[8] = {z0.x, z0.y, z0.z, z0.w, z1.x, z1.y, z1.z, z1.w};
            float xa[8];
            xa[0] = x0.x; xa[1] = x0.y; xa[2] = x0.z; xa[3] = x0.w;
            xa[4] = x1.x; xa[5] = x1.y; xa[6] = x1.z; xa[7] = x1.w;
            #pragma unroll
            for (int i = 0; i < 8; ++i)
                #pragma unroll
                for (int j = 0; j < 8; ++j)
                    acc[i][j] = fmaf(za[i], xa[j], acc[i][j]);
        }
    }

    // corr tile write (into d_out)
    float* cb = corr + (size_t)b * K_ * N_ + nt * 256;
    #pragma unroll
    for (int i = 0; i < 8; ++i) {
        float4 lo = make_float4(acc[i][0], acc[i][1], acc[i][2], acc[i][3]);
        float4 hi = make_float4(acc[i][4], acc[i][5], acc[i][6], acc[i][7]);
        *(float4*)&cb[(size_t)(tk * 8 + i) * N_ + tn * 8]     = lo;
        *(float4*)&cb[(size_t)(tk * 8 + i) * N_ + tn * 8 + 4] = hi;
    }
}

// ---------------------------------------------------------------------------
// Kernel B: pooling (x_h, x_w from corr) + conv1 + per-batch BN partial sums.
// grid 128 (one block per batch), block 256. Reads corr (L2/L3-resident).
// ---------------------------------------------------------------------------
__global__ __launch_bounds__(256) void kB_pool(const float* __restrict__ corr,
                                               const float* __restrict__ w1,
                                               const float* __restrict__ b1,
                                               float* __restrict__ ypre,
                                               float* __restrict__ psum)
{
    __shared__ float rs[4][1024];   // 16 KB: 4 channels of corr
    __shared__ float xc[64][64];    // 16 KB: xcat  [channel][l]
    __shared__ float w1s[TC_ * 64];
    __shared__ float ys[TC_ * 64];

    const int b   = blockIdx.x;
    const int tid = threadIdx.x;
    const float* cb = corr + (size_t)b * K_ * N_;

    if (tid < 128) *(float4*)&w1s[tid * 4] = *(const float4*)&w1[tid * 4];

    for (int pass = 0; pass < 16; ++pass) {
        #pragma unroll
        for (int i = 0; i < 4; ++i) {
            int q   = tid + i * 256;          // f4 id within 4-channel slab
            int kcl = q >> 8;
            int off = (q & 255) * 4;
            *(float4*)&rs[kcl][off] =
                *(const float4*)&cb[(size_t)(pass * 4 + kcl) * N_ + off];
        }
        __syncthreads();

        if (tid < 128) {                      // x_h: (kcl, h) sums over w
            int kcl = tid >> 5, h = tid & 31;
            float s = 0.f;
            #pragma unroll
            for (int m = 0; m < 8; ++m) {     // rotate f4 start by h: bank-balanced
                float4 v = *(float4*)&rs[kcl][h * 32 + (((m + h) & 7) << 2)];
                s += v.x + v.y + v.z + v.w;
            }
            xc[pass * 4 + kcl][h] = s * (1.f / 32.f);
        } else {                              // x_w: (kcl, w) sums over h
            int kcl = (tid - 128) >> 5, w = (tid - 128) & 31;
            float s = 0.f;
            #pragma unroll
            for (int h2 = 0; h2 < 32; ++h2) s += rs[kcl][h2 * 32 + w];
            xc[pass * 4 + kcl][32 + w] = s * (1.f / 32.f);
        }
        __syncthreads();
    }

    // conv1: y[o][l] = sum_k w1[o][k] * xc[k][l] + b1[o]
    const int o0 = tid >> 6;       // wave-uniform
    const int l  = tid & 63;
    float y0 = 0.f, y1 = 0.f;
    #pragma unroll 8
    for (int k = 0; k < 64; ++k) {
        float xv = xc[k][l];
        y0 = fmaf(w1s[o0 * 64 + k],       xv, y0);
        y1 = fmaf(w1s[(o0 + 4) * 64 + k], xv, y1);
    }
    y0 += b1[o0];
    y1 += b1[o0 + 4];
    ypre[((size_t)b * TC_ + o0)     * L_ + l] = y0;
    ypre[((size_t)b * TC_ + o0 + 4) * L_ + l] = y1;
    ys[o0 * L_ + l]       = y0;
    ys[(o0 + 4) * L_ + l] = y1;
    __syncthreads();

    if (tid < TC_) {               // per-batch BN partials (no atomics)
        float s = 0.f, sq = 0.f;
        #pragma unroll
        for (int m = 0; m < 16; ++m) {
            float4 v = *(float4*)&ys[tid * 64 + m * 4];
            s  += v.x + v.y + v.z + v.w;
            sq += v.x * v.x + v.y * v.y + v.z * v.z + v.w * v.w;
        }
        psum[b * 16 + tid]       = s;
        psum[b * 16 + 8 + tid]   = sq;
    }
}

// ---------------------------------------------------------------------------
// Kernel D: reduce BN partials, BN apply + h-swish, conv2/conv3 + sigmoid.
// grid 128, block 256.
// ---------------------------------------------------------------------------
__global__ __launch_bounds__(256) void kD_gate(const float* __restrict__ ypre,
                                               const float* __restrict__ psum,
                                               const float* __restrict__ gamma,
                                               const float* __restrict__ beta,
                                               const float* __restrict__ w2,
                                               const float* __restrict__ b2,
                                               const float* __restrict__ w3,
                                               const float* __restrict__ b3,
                                               float* __restrict__ outh,
                                               float* __restrict__ outw)
{
    __shared__ float sred[16][17];
    __shared__ float stats[16];
    __shared__ float yn[TC_ * L_];
    __shared__ float w2s[K_ * TC_];
    __shared__ float w3s[K_ * TC_];
    __shared__ float b2s[K_], b3s[K_];

    const int b   = blockIdx.x;
    const int tid = threadIdx.x;

    {   // reduce psum[128][16] -> stats[16]
        float p = 0.f;
        #pragma unroll
        for (int m = 0; m < 8; ++m) p += psum[tid + 256 * m];
        sred[tid & 15][tid >> 4] = p;
    }
    __syncthreads();
    if (tid < 16) {
        float s = 0.f;
        #pragma unroll
        for (int c = 0; c < 16; ++c) s += sred[tid][c];
        stats[tid] = s;
    }
    __syncthreads();

    const float inv_n = 1.f / (float)(B_ * L_);
    #pragma unroll
    for (int r = 0; r < 2; ++r) {
        int idx = tid + r * 256;
        int o   = idx >> 6;
        float mu  = stats[o] * inv_n;
        float var = stats[8 + o] * inv_n - mu * mu;
        float v = ypre[(size_t)b * TC_ * L_ + idx];
        v = (v - mu) * (1.f / sqrtf(var + EPS_)) * gamma[o] + beta[o];
        v = v * fminf(fmaxf(v + 3.f, 0.f), 6.f) * (1.f / 6.f);   // h_swish
        yn[idx] = v;
    }
    if (tid < 128)      *(float4*)&w2s[tid * 4]         = *(const float4*)&w2[tid * 4];
    else                *(float4*)&w3s[(tid - 128) * 4] = *(const float4*)&w3[(tid - 128) * 4];
    if (tid < 64)       b2s[tid]      = b2[tid];
    else if (tid < 128) b3s[tid - 64] = b3[tid - 64];
    __syncthreads();

    #pragma unroll
    for (int r = 0; r < 16; ++r) {
        int idx   = tid + r * 256;
        int which = idx >> 11;              // 0: out_h, 1: out_w
        int o     = (idx >> 5) & 63;
        int p     = idx & 31;
        const float* wsm = which ? w3s : w2s;
        const float* bsm = which ? b3s : b2s;
        float s = bsm[o];
        #pragma unroll
        for (int tt = 0; tt < TC_; ++tt)
            s = fmaf(wsm[o * TC_ + tt], yn[tt * L_ + which * H_ + p], s);
        s = 1.f / (1.f + __expf(-s));
        float* dst = which ? outw : outh;
        dst[((size_t)b * K_ + o) * H_ + p] = s;
    }
}

// ---------------------------------------------------------------------------
// Kernel E: out = corr * out_w[w] * out_h[h], in place on d_out. float4.
// ---------------------------------------------------------------------------
__global__ __launch_bounds__(256) void kE_final(float* __restrict__ out,
                                                const float* __restrict__ outh,
                                                const float* __restrict__ outw)
{
    int idx = blockIdx.x * 256 + threadIdx.x;   // f4 index
    int w4 = idx & 7;
    int h  = (idx >> 3) & 31;
    int bk = idx >> 8;                          // b*64 + k
    float4 c4 = ((const float4*)out)[idx];
    float  oh = outh[bk * H_ + h];
    float4 ow = *(const float4*)&outw[bk * H_ + w4 * 4];
    c4.x *= ow.x * oh;
    c4.y *= ow.y * oh;
    c4.z *= ow.z * oh;
    c4.w *= ow.w * oh;
    ((float4*)out)[idx] = c4;
}

// ---------------------------------------------------------------------------
extern "C" void kernel_launch(void* const* d_in, const int* in_sizes, int n_in,
                              void* d_out, int out_size, void* d_ws, size_t ws_size,
                              hipStream_t stream)
{
    const float* z     = (const float*)d_in[0];
    const float* x     = (const float*)d_in[1];
    const float* w1    = (const float*)d_in[2];
    const float* b1    = (const float*)d_in[3];
    const float* gamma = (const float*)d_in[4];
    const float* beta  = (const float*)d_in[5];
    const float* w2    = (const float*)d_in[6];
    const float* b2    = (const float*)d_in[7];
    const float* w3    = (const float*)d_in[8];
    const float* b3    = (const float*)d_in[9];
    float* out = (float*)d_out;
    float* ws  = (float*)d_ws;

    // workspace layout (floats), total 591,872 (~2.37 MB)
    float* ypre = ws;                  // B*8*64  = 65536
    float* psum = ws + 65536;          // B*16    = 2048
    float* outh = ws + 67584;          // B*64*32 = 262144
    float* outw = ws + 329728;         // B*64*32 = 262144

    kA_corr <<<dim3(4, B_), 256, 0, stream>>>(z, x, out);
    kB_pool <<<B_,          256, 0, stream>>>(out, w1, b1, ypre, psum);
    kD_gate <<<B_,          256, 0, stream>>>(ypre, psum, gamma, beta,
                                              w2, b2, w3, b3, outh, outw);
    kE_final<<<(B_ * K_ * N_) / (256 * 4), 256, 0, stream>>>(out, outh, outw);
}

// Round 6
// 266.838 us; speedup vs baseline: 1.1282x; 1.1220x over previous
//
#include <hip/hip_runtime.h>
#include <hip/hip_bf16.h>
#include <math.h>

// Problem constants
#define B_   128
#define C_   256
#define K_   64     // HZ*WZ (corr rows / channels)
#define N_   1024   // HX*WX (corr cols)
#define H_   32
#define W_   32
#define TC_  8
#define L_   64     // 2*H
#define EPS_ 1e-5f

typedef __attribute__((address_space(3))) void       as3_void;
typedef const __attribute__((address_space(1))) void as1_void;

__device__ __forceinline__ void gload16(const float* g, float* lds) {
    __builtin_amdgcn_global_load_lds((as1_void*)g, (as3_void*)lds, 16, 0, 0);
}

// ---------------------------------------------------------------------------
// Kernel A: per-batch corr = z^T x (64 x 1024, K=256). Pure GEMM, corr -> d_out.
// grid (4 n-tiles, 128 batches) = 512 blocks, block 256, 2 blocks/CU (80KB LDS).
// Block tile 64k x 256n; per-thread 8x8. Double-buffered LDS staged with
// global_load_lds(16B) — no staging VGPRs (R3/R4's reg-staging spilled: the
// allocator capped at 64 VGPRs and pushed 156MB/dispatch through scratch).
// amdgpu_waves_per_eu(1,2) pins the occupancy target so the budget is >=256.
// Counted-vmcnt pipeline (m201 pattern): stage next step's 10 glds/wave,
// s_waitcnt vmcnt(10) (never 0 mid-loop), raw s_barrier, compute, barrier.
// x 16B-slots pre-swizzled on the GLOBAL source with sigma(s)=s^((s>>4)&1)
// (involution; linear LDS dest per glds constraint), reads use sigma(slot) —
// measured 0 bank conflicts in R3/R4 with identical read geometry.
// ---------------------------------------------------------------------------
__global__ __launch_bounds__(256) __attribute__((amdgpu_waves_per_eu(1, 2)))
void kA_corr(const float* __restrict__ z,
             const float* __restrict__ x,
             float* __restrict__ corr)
{
    __shared__ float zs[2][32][64];    // 16 KB [buf][c][k]
    __shared__ float xs[2][32][256];   // 64 KB [buf][c][n] (16B slots swizzled)

    const int nt   = blockIdx.x;       // 0..3
    const int b    = blockIdx.y;
    const int tid  = threadIdx.x;
    const int wv   = tid >> 6;         // wave id 0..3
    const int lane = tid & 63;
    const int tk   = tid >> 5;         // 0..7  -> k0 = tk*8
    const int tn   = tid & 31;         // 0..31 -> n0 = tn*8

    const float* zb = z + (size_t)b * C_ * K_;
    const float* xb = x + (size_t)b * C_ * N_ + nt * 256;

    // sigma on 16B slots within a 64-slot x row
    const int sl = lane ^ ((lane >> 4) & 1);                 // source pre-swizzle
    const int s0 = (2 * tn)     ^ (((2 * tn)     >> 4) & 1); // read-side phys slots
    const int s1 = (2 * tn + 1) ^ (((2 * tn + 1) >> 4) & 1);

    // per-lane fixed parts of the staging addresses
    const float* zg = zb + (lane >> 4) * K_ + (lane & 15) * 4; // 4 rows x 16 slots
    const float* xg = xb + sl * 4;                             // 1 row  x 64 slots

    float acc[8][8] = {};

    // 40 chunks/step (8 z, 32 x), wave w takes ch = w + 4q, q=0..9
    auto stage = [&](int buf, int cs2) {
        const int cc = cs2 * 32;
        #pragma unroll
        for (int q = 0; q < 10; ++q) {
            const int ch = wv + 4 * q;          // wave-uniform
            if (ch < 8) {
                gload16(zg + (size_t)(cc + ch * 4) * K_, &zs[buf][ch * 4][0]);
            } else {
                gload16(xg + (size_t)(cc + ch - 8) * N_, &xs[buf][ch - 8][0]);
            }
        }
    };

    stage(0, 0);   // 10 glds in flight

    for (int cs = 0; cs < 8; ++cs) {
        const int cur = cs & 1;
        if (cs < 7) {
            stage(cur ^ 1, cs + 1);             // +10 in flight
            asm volatile("s_waitcnt vmcnt(10)" ::: "memory");  // cur landed, next flying
        } else {
            asm volatile("s_waitcnt vmcnt(0)" ::: "memory");
        }
        __builtin_amdgcn_s_barrier();           // all waves' cur-buf loads landed
        asm volatile("" ::: "memory");

        #pragma unroll 4
        for (int c = 0; c < 32; ++c) {
            float4 z0 = *(float4*)&zs[cur][c][tk * 8];
            float4 z1 = *(float4*)&zs[cur][c][tk * 8 + 4];
            float4 x0 = *(float4*)&xs[cur][c][s0 * 4];
            float4 x1 = *(float4*)&xs[cur][c][s1 * 4];
            float za[8] = {z0.x, z0.y, z0.z, z0.w, z1.x, z1.y, z1.z, z1.w};
            float xa[8] = {x0.x, x0.y, x0.z, x0.w, x1.x, x1.y, x1.z, x1.w};
            #pragma unroll
            for (int i = 0; i < 8; ++i)
                #pragma unroll
                for (int j = 0; j < 8; ++j)
                    acc[i][j] = fmaf(za[i], xa[j], acc[i][j]);
        }

        asm volatile("" ::: "memory");
        __builtin_amdgcn_s_barrier();           // readers done; next stage may overwrite
    }

    // corr tile write (into d_out)
    float* cb = corr + (size_t)b * K_ * N_ + nt * 256;
    #pragma unroll
    for (int i = 0; i < 8; ++i) {
        float4 lo = make_float4(acc[i][0], acc[i][1], acc[i][2], acc[i][3]);
        float4 hi = make_float4(acc[i][4], acc[i][5], acc[i][6], acc[i][7]);
        *(float4*)&cb[(size_t)(tk * 8 + i) * N_ + tn * 8]     = lo;
        *(float4*)&cb[(size_t)(tk * 8 + i) * N_ + tn * 8 + 4] = hi;
    }
}

// ---------------------------------------------------------------------------
// Kernel B: pooling (x_h, x_w from corr) + conv1 + per-batch BN partial sums.
// grid 128 (one block per batch), block 256. Reads corr (L2/L3-resident).
// ---------------------------------------------------------------------------
__global__ __launch_bounds__(256) void kB_pool(const float* __restrict__ corr,
                                               const float* __restrict__ w1,
                                               const float* __restrict__ b1,
                                               float* __restrict__ ypre,
                                               float* __restrict__ psum)
{
    __shared__ float rs[4][1024];   // 16 KB: 4 channels of corr
    __shared__ float xc[64][64];    // 16 KB: xcat  [channel][l]
    __shared__ float w1s[TC_ * 64];
    __shared__ float ys[TC_ * 64];

    const int b   = blockIdx.x;
    const int tid = threadIdx.x;
    const float* cb = corr + (size_t)b * K_ * N_;

    if (tid < 128) *(float4*)&w1s[tid * 4] = *(const float4*)&w1[tid * 4];

    for (int pass = 0; pass < 16; ++pass) {
        #pragma unroll
        for (int i = 0; i < 4; ++i) {
            int q   = tid + i * 256;          // f4 id within 4-channel slab
            int kcl = q >> 8;
            int off = (q & 255) * 4;
            *(float4*)&rs[kcl][off] =
                *(const float4*)&cb[(size_t)(pass * 4 + kcl) * N_ + off];
        }
        __syncthreads();

        if (tid < 128) {                      // x_h: (kcl, h) sums over w
            int kcl = tid >> 5, h = tid & 31;
            float s = 0.f;
            #pragma unroll
            for (int m = 0; m < 8; ++m) {     // rotate f4 start by h: bank-balanced
                float4 v = *(float4*)&rs[kcl][h * 32 + (((m + h) & 7) << 2)];
                s += v.x + v.y + v.z + v.w;
            }
            xc[pass * 4 + kcl][h] = s * (1.f / 32.f);
        } else {                              // x_w: (kcl, w) sums over h
            int kcl = (tid - 128) >> 5, w = (tid - 128) & 31;
            float s = 0.f;
            #pragma unroll
            for (int h2 = 0; h2 < 32; ++h2) s += rs[kcl][h2 * 32 + w];
            xc[pass * 4 + kcl][32 + w] = s * (1.f / 32.f);
        }
        __syncthreads();
    }

    // conv1: y[o][l] = sum_k w1[o][k] * xc[k][l] + b1[o]
    const int o0 = tid >> 6;       // wave-uniform
    const int l  = tid & 63;
    float y0 = 0.f, y1 = 0.f;
    #pragma unroll 8
    for (int k = 0; k < 64; ++k) {
        float xv = xc[k][l];
        y0 = fmaf(w1s[o0 * 64 + k],       xv, y0);
        y1 = fmaf(w1s[(o0 + 4) * 64 + k], xv, y1);
    }
    y0 += b1[o0];
    y1 += b1[o0 + 4];
    ypre[((size_t)b * TC_ + o0)     * L_ + l] = y0;
    ypre[((size_t)b * TC_ + o0 + 4) * L_ + l] = y1;
    ys[o0 * L_ + l]       = y0;
    ys[(o0 + 4) * L_ + l] = y1;
    __syncthreads();

    if (tid < TC_) {               // per-batch BN partials (no atomics)
        float s = 0.f, sq = 0.f;
        #pragma unroll
        for (int m = 0; m < 16; ++m) {
            float4 v = *(float4*)&ys[tid * 64 + m * 4];
            s  += v.x + v.y + v.z + v.w;
            sq += v.x * v.x + v.y * v.y + v.z * v.z + v.w * v.w;
        }
        psum[b * 16 + tid]       = s;
        psum[b * 16 + 8 + tid]   = sq;
    }
}

// ---------------------------------------------------------------------------
// Kernel D: reduce BN partials, BN apply + h-swish, conv2/conv3 + sigmoid.
// grid 128, block 256.
// ---------------------------------------------------------------------------
__global__ __launch_bounds__(256) void kD_gate(const float* __restrict__ ypre,
                                               const float* __restrict__ psum,
                                               const float* __restrict__ gamma,
                                               const float* __restrict__ beta,
                                               const float* __restrict__ w2,
                                               const float* __restrict__ b2,
                                               const float* __restrict__ w3,
                                               const float* __restrict__ b3,
                                               float* __restrict__ outh,
                                               float* __restrict__ outw)
{
    __shared__ float sred[16][17];
    __shared__ float stats[16];
    __shared__ float yn[TC_ * L_];
    __shared__ float w2s[K_ * TC_];
    __shared__ float w3s[K_ * TC_];
    __shared__ float b2s[K_], b3s[K_];

    const int b   = blockIdx.x;
    const int tid = threadIdx.x;

    {   // reduce psum[128][16] -> stats[16]
        float p = 0.f;
        #pragma unroll
        for (int m = 0; m < 8; ++m) p += psum[tid + 256 * m];
        sred[tid & 15][tid >> 4] = p;
    }
    __syncthreads();
    if (tid < 16) {
        float s = 0.f;
        #pragma unroll
        for (int c = 0; c < 16; ++c) s += sred[tid][c];
        stats[tid] = s;
    }
    __syncthreads();

    const float inv_n = 1.f / (float)(B_ * L_);
    #pragma unroll
    for (int r = 0; r < 2; ++r) {
        int idx = tid + r * 256;
        int o   = idx >> 6;
        float mu  = stats[o] * inv_n;
        float var = stats[8 + o] * inv_n - mu * mu;
        float v = ypre[(size_t)b * TC_ * L_ + idx];
        v = (v - mu) * (1.f / sqrtf(var + EPS_)) * gamma[o] + beta[o];
        v = v * fminf(fmaxf(v + 3.f, 0.f), 6.f) * (1.f / 6.f);   // h_swish
        yn[idx] = v;
    }
    if (tid < 128)      *(float4*)&w2s[tid * 4]         = *(const float4*)&w2[tid * 4];
    else                *(float4*)&w3s[(tid - 128) * 4] = *(const float4*)&w3[(tid - 128) * 4];
    if (tid < 64)       b2s[tid]      = b2[tid];
    else if (tid < 128) b3s[tid - 64] = b3[tid - 64];
    __syncthreads();

    #pragma unroll
    for (int r = 0; r < 16; ++r) {
        int idx   = tid + r * 256;
        int which = idx >> 11;              // 0: out_h, 1: out_w
        int o     = (idx >> 5) & 63;
        int p     = idx & 31;
        const float* wsm = which ? w3s : w2s;
        const float* bsm = which ? b3s : b2s;
        float s = bsm[o];
        #pragma unroll
        for (int tt = 0; tt < TC_; ++tt)
            s = fmaf(wsm[o * TC_ + tt], yn[tt * L_ + which * H_ + p], s);
        s = 1.f / (1.f + __expf(-s));
        float* dst = which ? outw : outh;
        dst[((size_t)b * K_ + o) * H_ + p] = s;
    }
}

// ---------------------------------------------------------------------------
// Kernel E: out = corr * out_w[w] * out_h[h], in place on d_out. float4.
// ---------------------------------------------------------------------------
__global__ __launch_bounds__(256) void kE_final(float* __restrict__ out,
                                                const float* __restrict__ outh,
                                                const float* __restrict__ outw)
{
    int idx = blockIdx.x * 256 + threadIdx.x;   // f4 index
    int w4 = idx & 7;
    int h  = (idx >> 3) & 31;
    int bk = idx >> 8;                          // b*64 + k
    float4 c4 = ((const float4*)out)[idx];
    float  oh = outh[bk * H_ + h];
    float4 ow = *(const float4*)&outw[bk * H_ + w4 * 4];
    c4.x *= ow.x * oh;
    c4.y *= ow.y * oh;
    c4.z *= ow.z * oh;
    c4.w *= ow.w * oh;
    ((float4*)out)[idx] = c4;
}

// ---------------------------------------------------------------------------
extern "C" void kernel_launch(void* const* d_in, const int* in_sizes, int n_in,
                              void* d_out, int out_size, void* d_ws, size_t ws_size,
                              hipStream_t stream)
{
    const float* z     = (const float*)d_in[0];
    const float* x     = (const float*)d_in[1];
    const float* w1    = (const float*)d_in[2];
    const float* b1    = (const float*)d_in[3];
    const float* gamma = (const float*)d_in[4];
    const float* beta  = (const float*)d_in[5];
    const float* w2    = (const float*)d_in[6];
    const float* b2    = (const float*)d_in[7];
    const float* w3    = (const float*)d_in[8];
    const float* b3    = (const float*)d_in[9];
    float* out = (float*)d_out;
    float* ws  = (float*)d_ws;

    // workspace layout (floats), total ~2.37 MB
    float* ypre = ws;                  // B*8*64  = 65536
    float* psum = ws + 65536;          // B*16    = 2048
    float* outh = ws + 67584;          // B*64*32 = 262144
    float* outw = ws + 329728;         // B*64*32 = 262144

    kA_corr <<<dim3(4, B_), 256, 0, stream>>>(z, x, out);
    kB_pool <<<B_,          256, 0, stream>>>(out, w1, b1, ypre, psum);
    kD_gate <<<B_,          256, 0, stream>>>(ypre, psum, gamma, beta,
                                              w2, b2, w3, b3, outh, outw);
    kE_final<<<(B_ * K_ * N_) / (256 * 4), 256, 0, stream>>>(out, outh, outw);
}